// Round 1
// baseline (355.070 us; speedup 1.0000x reference)
//
#include <hip/hip_runtime.h>

#define NB 32
#define CD 256
#define HH 32
#define WW 32
#define SS 1024
#define DD 256
#define TT 512
#define SCALE 0.0625f

typedef __attribute__((ext_vector_type(8))) short s16x8;
typedef __attribute__((ext_vector_type(4))) short s16x4;
typedef __attribute__((ext_vector_type(4))) float f32x4;

__device__ __forceinline__ unsigned short f2bf(float f) {
  unsigned u = __builtin_bit_cast(unsigned, f);
  u = (u + 0x7FFFu + ((u >> 16) & 1u)) >> 16;
  return (unsigned short)u;
}
__device__ __forceinline__ float bf2f(unsigned short h) {
  return __builtin_bit_cast(float, ((unsigned)h) << 16);
}

// ---------------- temb = relu(t @ W_t^T + b_t) : [N, C] ----------------
__global__ __launch_bounds__(256) void k_temb(const float* __restrict__ t,
    const float* __restrict__ Wt, const float* __restrict__ bt,
    float* __restrict__ temb) {
  const int n = blockIdx.x, c = threadIdx.x;
  const float4* tv = (const float4*)(t + (size_t)n * TT);
  const float4* wv = (const float4*)(Wt + (size_t)c * TT);
  float acc = 0.f;
#pragma unroll 8
  for (int i = 0; i < TT / 4; ++i) {
    float4 a = tv[i], b = wv[i];
    acc += a.x * b.x + a.y * b.y + a.z * b.z + a.w * b.w;
  }
  acc += bt[c];
  temb[n * CD + c] = fmaxf(acc, 0.f);
}

// ---------------- weights fp32 -> bf16 (q,k,v,p concatenated) ----------------
__global__ __launch_bounds__(256) void k_wconv(const float* __restrict__ wq,
    const float* __restrict__ wk, const float* __restrict__ wv,
    const float* __restrict__ wp, unsigned short* __restrict__ dst) {
  const int i = blockIdx.x * 256 + threadIdx.x;  // 4*65536 total
  const int which = i >> 16, off = i & 65535;
  const float* s = which == 0 ? wq : which == 1 ? wk : which == 2 ? wv : wp;
  dst[i] = f2bf(s[off]);
}

// ------- xb[n, s=w*H+h, c] = bf16(x[n,c,h,w] + temb[n,c]) -------
__global__ __launch_bounds__(256) void k_addT(const float* __restrict__ x,
    const float* __restrict__ temb, unsigned short* __restrict__ xb) {
  __shared__ float tile[32][33];
  const int tx = threadIdx.x & 31, ty = threadIdx.x >> 5;
  const int n = blockIdx.z, h = blockIdx.y, c0 = blockIdx.x * 32;
  const float* xp = x + (((size_t)n * CD + c0) * HH + h) * WW;
#pragma unroll
  for (int i = 0; i < 4; ++i) {
    const int cc = ty + i * 8;
    tile[cc][tx] = xp[(size_t)cc * HH * WW + tx] + temb[n * CD + c0 + cc];
  }
  __syncthreads();
  unsigned short* op = xb + ((size_t)n * SS + h) * CD + c0;
#pragma unroll
  for (int i = 0; i < 4; ++i) {
    const int ww = ty + i * 8;
    op[(size_t)ww * HH * CD + tx] = f2bf(tile[tx][ww]);
  }
}

// ------- GEMM: Out[n, s, d] = sum_c A[n, s, c] * B[d, c]  (128x128 tile, BK=32)
// transposed=1 writes Out[n, d, s] instead (for V^T).
__global__ __launch_bounds__(256) void k_gemm(const unsigned short* __restrict__ A,
    const unsigned short* __restrict__ B, unsigned short* __restrict__ Out,
    const int transposed) {
  __shared__ __attribute__((aligned(16))) unsigned short As[128 * 32];
  __shared__ __attribute__((aligned(16))) unsigned short Bs[128 * 32];
  const int n = blockIdx.z;
  const int s0 = blockIdx.x * 128;
  const int d0 = blockIdx.y * 128;
  const int tid = threadIdx.x;
  const int lane = tid & 63, wid = tid >> 6;
  const int lo = lane & 15, hi = lane >> 4;
  const int wr = wid >> 1, wc = wid & 1;
  const unsigned short* An = A + (size_t)n * SS * CD;
  f32x4 acc[4][4] = {};
  for (int k0 = 0; k0 < CD; k0 += 32) {
#pragma unroll
    for (int i = 0; i < 2; ++i) {
      const int seg = i * 256 + wid * 64 + lane;
      const int row = seg >> 2, c8 = seg & 3;
      const unsigned short* ga = An + (size_t)(s0 + row) * CD + k0 + c8 * 8;
      __builtin_amdgcn_global_load_lds(
          (const __attribute__((address_space(1))) unsigned int*)(const void*)ga,
          (__attribute__((address_space(3))) unsigned int*)(void*)(As + (size_t)(i * 256 + wid * 64) * 8),
          16, 0, 0);
      const unsigned short* gb = B + (size_t)(d0 + row) * CD + k0 + c8 * 8;
      __builtin_amdgcn_global_load_lds(
          (const __attribute__((address_space(1))) unsigned int*)(const void*)gb,
          (__attribute__((address_space(3))) unsigned int*)(void*)(Bs + (size_t)(i * 256 + wid * 64) * 8),
          16, 0, 0);
    }
    __syncthreads();
    s16x8 a[4], b[4];
#pragma unroll
    for (int mi = 0; mi < 4; ++mi)
      a[mi] = *(const s16x8*)&As[(wr * 64 + mi * 16 + lo) * 32 + hi * 8];
#pragma unroll
    for (int ni = 0; ni < 4; ++ni)
      b[ni] = *(const s16x8*)&Bs[(wc * 64 + ni * 16 + lo) * 32 + hi * 8];
#pragma unroll
    for (int mi = 0; mi < 4; ++mi)
#pragma unroll
      for (int ni = 0; ni < 4; ++ni)
        acc[mi][ni] = __builtin_amdgcn_mfma_f32_16x16x32_bf16(a[mi], b[ni], acc[mi][ni], 0, 0, 0);
    __syncthreads();
  }
  if (!transposed) {
    unsigned short* On = Out + (size_t)n * SS * DD;
#pragma unroll
    for (int mi = 0; mi < 4; ++mi) {
      const int r0 = s0 + wr * 64 + mi * 16 + hi * 4;
#pragma unroll
      for (int ni = 0; ni < 4; ++ni) {
        const int col = d0 + wc * 64 + ni * 16 + lo;
#pragma unroll
        for (int r = 0; r < 4; ++r)
          On[(size_t)(r0 + r) * DD + col] = f2bf(acc[mi][ni][r]);
      }
    }
  } else {
    unsigned short* On = Out + (size_t)n * DD * SS;
#pragma unroll
    for (int mi = 0; mi < 4; ++mi) {
      const int r0 = s0 + wr * 64 + mi * 16 + hi * 4;
#pragma unroll
      for (int ni = 0; ni < 4; ++ni) {
        const int col = d0 + wc * 64 + ni * 16 + lo;
        s16x4 v;
#pragma unroll
        for (int r = 0; r < 4; ++r) v[r] = (short)f2bf(acc[mi][ni][r]);
        *(s16x4*)&On[(size_t)col * SS + r0] = v;
      }
    }
  }
}

// ------- flash attention: per (n, q-tile of 64). 4 waves, 16 q-rows each. -------
__global__ __launch_bounds__(256) void k_attn(const unsigned short* __restrict__ qb,
    const unsigned short* __restrict__ kb, const unsigned short* __restrict__ vtb,
    unsigned short* __restrict__ ob) {
  __shared__ __attribute__((aligned(16))) unsigned short P[4][16][72];
  const int n = blockIdx.y, qt = blockIdx.x;
  const int tid = threadIdx.x, lane = tid & 63, w = tid >> 6;
  const int lo = lane & 15, hi = lane >> 4;
  const int qrow = qt * 64 + w * 16 + lo;
  const unsigned short* Qp = qb + ((size_t)n * SS + qrow) * DD + hi * 8;
  s16x8 q[8];
#pragma unroll
  for (int ki = 0; ki < 8; ++ki) q[ki] = *(const s16x8*)(Qp + ki * 32);
  f32x4 acco[16] = {};
  float mrun[4], lrun[4];
#pragma unroll
  for (int r = 0; r < 4; ++r) { mrun[r] = -3.0e38f; lrun[r] = 0.f; }
  const unsigned short* Kn = kb + (size_t)n * SS * DD;
  const unsigned short* Vn = vtb + (size_t)n * DD * SS;
  for (int jt = 0; jt < 16; ++jt) {
    const int j0 = jt * 64;
    f32x4 sc[4] = {};
#pragma unroll
    for (int jf = 0; jf < 4; ++jf) {
      const unsigned short* Kp = Kn + (size_t)(j0 + jf * 16 + lo) * DD + hi * 8;
#pragma unroll
      for (int ki = 0; ki < 8; ++ki) {
        s16x8 kf = *(const s16x8*)(Kp + ki * 32);
        sc[jf] = __builtin_amdgcn_mfma_f32_16x16x32_bf16(q[ki], kf, sc[jf], 0, 0, 0);
      }
    }
    float tmax[4];
#pragma unroll
    for (int r = 0; r < 4; ++r) {
      sc[0][r] *= SCALE; sc[1][r] *= SCALE; sc[2][r] *= SCALE; sc[3][r] *= SCALE;
      tmax[r] = fmaxf(fmaxf(sc[0][r], sc[1][r]), fmaxf(sc[2][r], sc[3][r]));
    }
#pragma unroll
    for (int off = 1; off < 16; off <<= 1)
#pragma unroll
      for (int r = 0; r < 4; ++r)
        tmax[r] = fmaxf(tmax[r], __shfl_xor(tmax[r], off, 64));
    float corr[4];
#pragma unroll
    for (int r = 0; r < 4; ++r) {
      const float mn = fmaxf(mrun[r], tmax[r]);
      corr[r] = __expf(mrun[r] - mn);
      mrun[r] = mn;
    }
    f32x4 p[4];
#pragma unroll
    for (int jf = 0; jf < 4; ++jf)
#pragma unroll
      for (int r = 0; r < 4; ++r)
        p[jf][r] = __expf(sc[jf][r] - mrun[r]);
    float rs[4];
#pragma unroll
    for (int r = 0; r < 4; ++r) rs[r] = p[0][r] + p[1][r] + p[2][r] + p[3][r];
#pragma unroll
    for (int off = 1; off < 16; off <<= 1)
#pragma unroll
      for (int r = 0; r < 4; ++r) rs[r] += __shfl_xor(rs[r], off, 64);
#pragma unroll
    for (int r = 0; r < 4; ++r) lrun[r] = lrun[r] * corr[r] + rs[r];
#pragma unroll
    for (int df = 0; df < 16; ++df)
#pragma unroll
      for (int r = 0; r < 4; ++r) acco[df][r] *= corr[r];
#pragma unroll
    for (int jf = 0; jf < 4; ++jf)
#pragma unroll
      for (int r = 0; r < 4; ++r)
        P[w][hi * 4 + r][jf * 16 + lo] = f2bf(p[jf][r]);
    __syncthreads();
#pragma unroll
    for (int kj = 0; kj < 2; ++kj) {
      const s16x8 pa = *(const s16x8*)&P[w][lo][kj * 32 + hi * 8];
      const unsigned short* Vp = Vn + j0 + kj * 32 + hi * 8;
#pragma unroll
      for (int df = 0; df < 16; ++df) {
        s16x8 vf = *(const s16x8*)(Vp + (size_t)(df * 16 + lo) * SS);
        acco[df] = __builtin_amdgcn_mfma_f32_16x16x32_bf16(pa, vf, acco[df], 0, 0, 0);
      }
    }
    __syncthreads();
  }
  float inv[4];
#pragma unroll
  for (int r = 0; r < 4; ++r) inv[r] = 1.0f / lrun[r];
  unsigned short* On = ob + ((size_t)n * SS + qt * 64 + w * 16) * DD;
#pragma unroll
  for (int df = 0; df < 16; ++df)
#pragma unroll
    for (int r = 0; r < 4; ++r)
      On[(size_t)(hi * 4 + r) * DD + df * 16 + lo] = f2bf(acco[df][r] * inv[r]);
}

// ------- out[n,c,h,w] = proj[n, s=w*H+h, c] + bp[c] + x[n,c,h,w] -------
__global__ __launch_bounds__(256) void k_out(const unsigned short* __restrict__ projb,
    const float* __restrict__ x, const float* __restrict__ bp, float* __restrict__ out) {
  __shared__ float tile[32][33];
  const int tx = threadIdx.x & 31, ty = threadIdx.x >> 5;
  const int n = blockIdx.z, h = blockIdx.y, c0 = blockIdx.x * 32;
  const unsigned short* pp = projb + ((size_t)n * SS + h) * CD + c0;
#pragma unroll
  for (int i = 0; i < 4; ++i) {
    const int ww = ty + i * 8;
    tile[ww][tx] = bf2f(pp[(size_t)ww * HH * CD + tx]);
  }
  __syncthreads();
  const float* xp = x + (((size_t)n * CD + c0) * HH + h) * WW;
  float* op = out + (((size_t)n * CD + c0) * HH + h) * WW;
#pragma unroll
  for (int i = 0; i < 4; ++i) {
    const int cc = ty + i * 8;
    op[(size_t)cc * HH * WW + tx] = tile[tx][cc] + bp[c0 + cc] + xp[(size_t)cc * HH * WW + tx];
  }
}

extern "C" void kernel_launch(void* const* d_in, const int* in_sizes, int n_in,
                              void* d_out, int out_size, void* d_ws, size_t ws_size,
                              hipStream_t stream) {
  const float* x  = (const float*)d_in[0];
  const float* t  = (const float*)d_in[1];
  const float* Wt = (const float*)d_in[2];
  const float* bt = (const float*)d_in[3];
  const float* Wq = (const float*)d_in[4];
  const float* Wk = (const float*)d_in[5];
  const float* Wv = (const float*)d_in[6];
  const float* Wp = (const float*)d_in[7];
  const float* bp = (const float*)d_in[8];
  char* ws = (char*)d_ws;
  float* temb        = (float*)ws;                              // 32 KB
  unsigned short* wb = (unsigned short*)(ws + 32768);           // 512 KB (q,k,v,p)
  unsigned short* xb = (unsigned short*)(ws + 557056);          // 16 MB
  unsigned short* qb = (unsigned short*)(ws + 17334272);        // 16 MB
  unsigned short* kb = (unsigned short*)(ws + 34111488);        // 16 MB
  unsigned short* vtb = (unsigned short*)(ws + 50888704);       // 16 MB [N, D, S]
  unsigned short* ob = (unsigned short*)(ws + 67665920);        // 16 MB
  unsigned short* projb = xb;                                   // reuse xb
  float* out = (float*)d_out;

  k_temb<<<32, 256, 0, stream>>>(t, Wt, bt, temb);
  k_wconv<<<1024, 256, 0, stream>>>(Wq, Wk, Wv, Wp, wb);
  k_addT<<<dim3(8, 32, 32), 256, 0, stream>>>(x, temb, xb);
  k_gemm<<<dim3(8, 2, 32), 256, 0, stream>>>(xb, wb,          qb,  0);
  k_gemm<<<dim3(8, 2, 32), 256, 0, stream>>>(xb, wb + 65536,  kb,  0);
  k_gemm<<<dim3(8, 2, 32), 256, 0, stream>>>(xb, wb + 131072, vtb, 1);
  k_attn<<<dim3(16, 32), 256, 0, stream>>>(qb, kb, vtb, ob);
  k_gemm<<<dim3(8, 2, 32), 256, 0, stream>>>(ob, wb + 196608, projb, 0);
  k_out<<<dim3(8, 32, 32), 256, 0, stream>>>(projb, x, bp, out);
}

// Round 2
// 171.059 us; speedup vs baseline: 2.0757x; 2.0757x over previous
//
#include <hip/hip_runtime.h>

#define NB 32
#define CD 256
#define HH 32
#define WW 32
#define SS 1024
#define DD 256
#define TT 512
#define SCALE 0.0625f

typedef __attribute__((ext_vector_type(8))) short s16x8;
typedef __attribute__((ext_vector_type(4))) short s16x4;
typedef __attribute__((ext_vector_type(4))) float f32x4;

__device__ __forceinline__ unsigned short f2bf(float f) {
  unsigned u = __builtin_bit_cast(unsigned, f);
  u = (u + 0x7FFFu + ((u >> 16) & 1u)) >> 16;
  return (unsigned short)u;
}
__device__ __forceinline__ float bf2f(unsigned short h) {
  return __builtin_bit_cast(float, ((unsigned)h) << 16);
}

// ---------------- temb = relu(t @ W_t^T + b_t) : [N, C] ----------------
__global__ __launch_bounds__(256) void k_temb(const float* __restrict__ t,
    const float* __restrict__ Wt, const float* __restrict__ bt,
    float* __restrict__ temb) {
  const int n = blockIdx.x, c = threadIdx.x;
  const float4* tv = (const float4*)(t + (size_t)n * TT);
  const float4* wv = (const float4*)(Wt + (size_t)c * TT);
  float acc = 0.f;
#pragma unroll 8
  for (int i = 0; i < TT / 4; ++i) {
    float4 a = tv[i], b = wv[i];
    acc += a.x * b.x + a.y * b.y + a.z * b.z + a.w * b.w;
  }
  acc += bt[c];
  temb[n * CD + c] = fmaxf(acc, 0.f);
}

// ---------------- weights fp32 -> bf16 (q,k,v,p concatenated) ----------------
__global__ __launch_bounds__(256) void k_wconv(const float* __restrict__ wq,
    const float* __restrict__ wk, const float* __restrict__ wv,
    const float* __restrict__ wp, unsigned short* __restrict__ dst) {
  const int i = blockIdx.x * 256 + threadIdx.x;  // 4*65536 total
  const int which = i >> 16, off = i & 65535;
  const float* s = which == 0 ? wq : which == 1 ? wk : which == 2 ? wv : wp;
  dst[i] = f2bf(s[off]);
}

// ------- xb[n, s=w*H+h, c] = bf16(x[n,c,h,w] + temb[n,c]) -------
__global__ __launch_bounds__(256) void k_addT(const float* __restrict__ x,
    const float* __restrict__ temb, unsigned short* __restrict__ xb) {
  __shared__ float tile[32][33];
  const int tx = threadIdx.x & 31, ty = threadIdx.x >> 5;
  const int n = blockIdx.z, h = blockIdx.y, c0 = blockIdx.x * 32;
  const float* xp = x + (((size_t)n * CD + c0) * HH + h) * WW;
#pragma unroll
  for (int i = 0; i < 4; ++i) {
    const int cc = ty + i * 8;
    tile[cc][tx] = xp[(size_t)cc * HH * WW + tx] + temb[n * CD + c0 + cc];
  }
  __syncthreads();
  unsigned short* op = xb + ((size_t)n * SS + h) * CD + c0;
#pragma unroll
  for (int i = 0; i < 4; ++i) {
    const int ww = ty + i * 8;
    op[(size_t)ww * HH * CD + tx] = f2bf(tile[tx][ww]);
  }
}

// ------- GEMM: Out[n, s, d] = oscale * sum_c A[n, s, c] * B[d, c]
// transposed=1 writes Out[n, d, s] instead (for V^T).
__global__ __launch_bounds__(256) void k_gemm(const unsigned short* __restrict__ A,
    const unsigned short* __restrict__ B, unsigned short* __restrict__ Out,
    const int transposed, const float oscale) {
  __shared__ __attribute__((aligned(16))) unsigned short As[128 * 32];
  __shared__ __attribute__((aligned(16))) unsigned short Bs[128 * 32];
  const int n = blockIdx.z;
  const int s0 = blockIdx.x * 128;
  const int d0 = blockIdx.y * 128;
  const int tid = threadIdx.x;
  const int lane = tid & 63, wid = tid >> 6;
  const int lo = lane & 15, hi = lane >> 4;
  const int wr = wid >> 1, wc = wid & 1;
  const unsigned short* An = A + (size_t)n * SS * CD;
  f32x4 acc[4][4] = {};
  for (int k0 = 0; k0 < CD; k0 += 32) {
#pragma unroll
    for (int i = 0; i < 2; ++i) {
      const int seg = i * 256 + wid * 64 + lane;
      const int row = seg >> 2, c8 = seg & 3;
      const unsigned short* ga = An + (size_t)(s0 + row) * CD + k0 + c8 * 8;
      __builtin_amdgcn_global_load_lds(
          (const __attribute__((address_space(1))) unsigned int*)(const void*)ga,
          (__attribute__((address_space(3))) unsigned int*)(void*)(As + (size_t)(i * 256 + wid * 64) * 8),
          16, 0, 0);
      const unsigned short* gb = B + (size_t)(d0 + row) * CD + k0 + c8 * 8;
      __builtin_amdgcn_global_load_lds(
          (const __attribute__((address_space(1))) unsigned int*)(const void*)gb,
          (__attribute__((address_space(3))) unsigned int*)(void*)(Bs + (size_t)(i * 256 + wid * 64) * 8),
          16, 0, 0);
    }
    __syncthreads();
    s16x8 a[4], b[4];
#pragma unroll
    for (int mi = 0; mi < 4; ++mi)
      a[mi] = *(const s16x8*)&As[(wr * 64 + mi * 16 + lo) * 32 + hi * 8];
#pragma unroll
    for (int ni = 0; ni < 4; ++ni)
      b[ni] = *(const s16x8*)&Bs[(wc * 64 + ni * 16 + lo) * 32 + hi * 8];
#pragma unroll
    for (int mi = 0; mi < 4; ++mi)
#pragma unroll
      for (int ni = 0; ni < 4; ++ni)
        acc[mi][ni] = __builtin_amdgcn_mfma_f32_16x16x32_bf16(a[mi], b[ni], acc[mi][ni], 0, 0, 0);
    __syncthreads();
  }
  if (!transposed) {
    unsigned short* On = Out + (size_t)n * SS * DD;
#pragma unroll
    for (int mi = 0; mi < 4; ++mi) {
      const int r0 = s0 + wr * 64 + mi * 16 + hi * 4;
#pragma unroll
      for (int ni = 0; ni < 4; ++ni) {
        const int col = d0 + wc * 64 + ni * 16 + lo;
#pragma unroll
        for (int r = 0; r < 4; ++r)
          On[(size_t)(r0 + r) * DD + col] = f2bf(acc[mi][ni][r] * oscale);
      }
    }
  } else {
    unsigned short* On = Out + (size_t)n * DD * SS;
#pragma unroll
    for (int mi = 0; mi < 4; ++mi) {
      const int r0 = s0 + wr * 64 + mi * 16 + hi * 4;
#pragma unroll
      for (int ni = 0; ni < 4; ++ni) {
        const int col = d0 + wc * 64 + ni * 16 + lo;
        s16x4 v;
#pragma unroll
        for (int r = 0; r < 4; ++r) v[r] = (short)f2bf(acc[mi][ni][r] * oscale);
        *(s16x4*)&On[(size_t)col * SS + r0] = v;
      }
    }
  }
}

// ------- flash attention: 256 blocks (n = bid&31, qt = bid>>5), 4 waves,
// 32 q-rows per wave. K/V^T tiles (KVBLK=64) staged in LDS, double-buffered,
// XOR-swizzled; P routed per-wave through padded LDS (no barrier needed).
__global__ __launch_bounds__(256) void k_attn(const unsigned short* __restrict__ qb,
    const unsigned short* __restrict__ kb, const unsigned short* __restrict__ vtb,
    unsigned short* __restrict__ ob) {
  // layout (ushort elems): Ks[2][64*256] @0, Vs[2][256*64] @32768, P[4][32*72] @65536
  __shared__ __attribute__((aligned(16))) unsigned short lds[74752];
  const int b = blockIdx.x;
  const int n = b & 31, qt = b >> 5;
  const int tid = threadIdx.x, lane = tid & 63, w = tid >> 6;
  const int lo = lane & 15, hi = lane >> 4;
  const unsigned short* Kn = kb + (size_t)n * SS * DD;
  const unsigned short* Vn = vtb + (size_t)n * DD * SS;
  unsigned short* Pw = lds + 65536 + w * 2304;  // [32][72]

  const int q0 = qt * 128 + w * 32;
  s16x8 q[2][8];
#pragma unroll
  for (int m = 0; m < 2; ++m) {
    const unsigned short* Qp = qb + ((size_t)n * SS + q0 + m * 16 + lo) * DD + hi * 8;
#pragma unroll
    for (int ki = 0; ki < 8; ++ki) q[m][ki] = *(const s16x8*)(Qp + ki * 32);
  }

  f32x4 acco[2][16] = {};
  float mrun[2][4], lrun[2][4];
#pragma unroll
  for (int m = 0; m < 2; ++m)
#pragma unroll
    for (int r = 0; r < 4; ++r) { mrun[m][r] = -3.0e38f; lrun[m][r] = 0.f; }

  auto STAGE = [&](int buf, int jt) {
    const int j0 = jt * 64;
    unsigned short* Ks = lds + buf * 16384;
    unsigned short* Vs = lds + 32768 + buf * 16384;
#pragma unroll
    for (int i = 0; i < 8; ++i) {
      const int rK = i * 8 + w * 2 + (lane >> 5);
      const int cb = (lane & 31) ^ (rK & 7);
      const unsigned short* g = Kn + (size_t)(j0 + rK) * DD + cb * 8;
      __builtin_amdgcn_global_load_lds(
          (const __attribute__((address_space(1))) unsigned int*)(const void*)g,
          (__attribute__((address_space(3))) unsigned int*)(void*)(Ks + (i * 8 + w * 2) * 256),
          16, 0, 0);
    }
#pragma unroll
    for (int i = 0; i < 8; ++i) {
      const int dV = i * 32 + w * 8 + (lane >> 3);
      const int jb = (lane & 7) ^ (dV & 7);
      const unsigned short* g = Vn + (size_t)dV * SS + j0 + jb * 8;
      __builtin_amdgcn_global_load_lds(
          (const __attribute__((address_space(1))) unsigned int*)(const void*)g,
          (__attribute__((address_space(3))) unsigned int*)(void*)(Vs + (i * 32 + w * 8) * 64),
          16, 0, 0);
    }
  };

  STAGE(0, 0);
  __syncthreads();  // vmcnt(0) drain + barrier: tile 0 ready

  int cur = 0;
#pragma unroll 1
  for (int jt = 0; jt < 16; ++jt) {
    if (jt + 1 < 16) STAGE(cur ^ 1, jt + 1);  // async prefetch of next tile
    const unsigned short* Ks = lds + cur * 16384;
    const unsigned short* Vs = lds + 32768 + cur * 16384;
    // ---- QK^T: sc[m][jf] = Q[m] · K-tile, 64 j-cols ----
    f32x4 sc[2][4] = {};
#pragma unroll
    for (int ki = 0; ki < 8; ++ki) {
      s16x8 kf[4];
#pragma unroll
      for (int jf = 0; jf < 4; ++jf) {
        const int r = jf * 16 + lo;
        kf[jf] = *(const s16x8*)&Ks[r * 256 + (((ki * 4 + hi) ^ (r & 7)) << 3)];
      }
#pragma unroll
      for (int jf = 0; jf < 4; ++jf) {
        sc[0][jf] = __builtin_amdgcn_mfma_f32_16x16x32_bf16(q[0][ki], kf[jf], sc[0][jf], 0, 0, 0);
        sc[1][jf] = __builtin_amdgcn_mfma_f32_16x16x32_bf16(q[1][ki], kf[jf], sc[1][jf], 0, 0, 0);
      }
    }
    // ---- online softmax (scale folded into Q; defer-max THR=8) ----
    float tmax[2][4];
#pragma unroll
    for (int m = 0; m < 2; ++m)
#pragma unroll
      for (int r = 0; r < 4; ++r)
        tmax[m][r] = fmaxf(fmaxf(sc[m][0][r], sc[m][1][r]), fmaxf(sc[m][2][r], sc[m][3][r]));
#pragma unroll
    for (int off = 1; off < 16; off <<= 1)
#pragma unroll
      for (int m = 0; m < 2; ++m)
#pragma unroll
        for (int r = 0; r < 4; ++r)
          tmax[m][r] = fmaxf(tmax[m][r], __shfl_xor(tmax[m][r], off, 64));
    int need = 0;
#pragma unroll
    for (int m = 0; m < 2; ++m)
#pragma unroll
      for (int r = 0; r < 4; ++r)
        need |= (tmax[m][r] > mrun[m][r] + 8.f) ? 1 : 0;
    if (__any(need)) {
      float corr[2][4];
#pragma unroll
      for (int m = 0; m < 2; ++m)
#pragma unroll
        for (int r = 0; r < 4; ++r) {
          const float mn = fmaxf(mrun[m][r], tmax[m][r]);
          corr[m][r] = __expf(mrun[m][r] - mn);
          mrun[m][r] = mn;
          lrun[m][r] *= corr[m][r];
        }
#pragma unroll
      for (int m = 0; m < 2; ++m)
#pragma unroll
        for (int df = 0; df < 16; ++df)
#pragma unroll
          for (int r = 0; r < 4; ++r) acco[m][df][r] *= corr[m][r];
    }
#pragma unroll
    for (int m = 0; m < 2; ++m)
#pragma unroll
      for (int jf = 0; jf < 4; ++jf)
#pragma unroll
        for (int r = 0; r < 4; ++r)
          sc[m][jf][r] = __expf(sc[m][jf][r] - mrun[m][r]);
    float rs[2][4];
#pragma unroll
    for (int m = 0; m < 2; ++m)
#pragma unroll
      for (int r = 0; r < 4; ++r)
        rs[m][r] = (sc[m][0][r] + sc[m][1][r]) + (sc[m][2][r] + sc[m][3][r]);
#pragma unroll
    for (int off = 1; off < 16; off <<= 1)
#pragma unroll
      for (int m = 0; m < 2; ++m)
#pragma unroll
        for (int r = 0; r < 4; ++r)
          rs[m][r] += __shfl_xor(rs[m][r], off, 64);
#pragma unroll
    for (int m = 0; m < 2; ++m)
#pragma unroll
      for (int r = 0; r < 4; ++r) lrun[m][r] += rs[m][r];
    // ---- P -> per-wave LDS (bf16), no barrier: same-wave write->read ----
#pragma unroll
    for (int m = 0; m < 2; ++m)
#pragma unroll
      for (int jf = 0; jf < 4; ++jf)
#pragma unroll
        for (int r = 0; r < 4; ++r)
          Pw[(m * 16 + hi * 4 + r) * 72 + jf * 16 + lo] = f2bf(sc[m][jf][r]);
    // ---- PV: acco[m][df] += P[m] · V^T-tile ----
#pragma unroll
    for (int kj = 0; kj < 2; ++kj) {
      s16x8 pa[2];
#pragma unroll
      for (int m = 0; m < 2; ++m)
        pa[m] = *(const s16x8*)&Pw[(m * 16 + lo) * 72 + kj * 32 + hi * 8];
#pragma unroll
      for (int df = 0; df < 16; ++df) {
        const int d = df * 16 + lo;
        const s16x8 vf = *(const s16x8*)&Vs[d * 64 + (((kj * 4 + hi) ^ (d & 7)) << 3)];
        acco[0][df] = __builtin_amdgcn_mfma_f32_16x16x32_bf16(pa[0], vf, acco[0][df], 0, 0, 0);
        acco[1][df] = __builtin_amdgcn_mfma_f32_16x16x32_bf16(pa[1], vf, acco[1][df], 0, 0, 0);
      }
    }
    __syncthreads();  // drains vmcnt(0): next tile landed; all waves done with cur
    cur ^= 1;
  }
  float inv[2][4];
#pragma unroll
  for (int m = 0; m < 2; ++m)
#pragma unroll
    for (int r = 0; r < 4; ++r) inv[m][r] = 1.0f / lrun[m][r];
#pragma unroll
  for (int m = 0; m < 2; ++m) {
    unsigned short* On = ob + ((size_t)n * SS + q0 + m * 16) * DD;
#pragma unroll
    for (int df = 0; df < 16; ++df)
#pragma unroll
      for (int r = 0; r < 4; ++r)
        On[(size_t)(hi * 4 + r) * DD + df * 16 + lo] = f2bf(acco[m][df][r] * inv[m][r]);
  }
}

// ------- out[n,c,h,w] = proj[n, s=w*H+h, c] + bp[c] + x[n,c,h,w] -------
__global__ __launch_bounds__(256) void k_out(const unsigned short* __restrict__ projb,
    const float* __restrict__ x, const float* __restrict__ bp, float* __restrict__ out) {
  __shared__ float tile[32][33];
  const int tx = threadIdx.x & 31, ty = threadIdx.x >> 5;
  const int n = blockIdx.z, h = blockIdx.y, c0 = blockIdx.x * 32;
  const unsigned short* pp = projb + ((size_t)n * SS + h) * CD + c0;
#pragma unroll
  for (int i = 0; i < 4; ++i) {
    const int ww = ty + i * 8;
    tile[ww][tx] = bf2f(pp[(size_t)ww * HH * CD + tx]);
  }
  __syncthreads();
  const float* xp = x + (((size_t)n * CD + c0) * HH + h) * WW;
  float* op = out + (((size_t)n * CD + c0) * HH + h) * WW;
#pragma unroll
  for (int i = 0; i < 4; ++i) {
    const int cc = ty + i * 8;
    op[(size_t)cc * HH * WW + tx] = tile[tx][cc] + bp[c0 + cc] + xp[(size_t)cc * HH * WW + tx];
  }
}

extern "C" void kernel_launch(void* const* d_in, const int* in_sizes, int n_in,
                              void* d_out, int out_size, void* d_ws, size_t ws_size,
                              hipStream_t stream) {
  const float* x  = (const float*)d_in[0];
  const float* t  = (const float*)d_in[1];
  const float* Wt = (const float*)d_in[2];
  const float* bt = (const float*)d_in[3];
  const float* Wq = (const float*)d_in[4];
  const float* Wk = (const float*)d_in[5];
  const float* Wv = (const float*)d_in[6];
  const float* Wp = (const float*)d_in[7];
  const float* bp = (const float*)d_in[8];
  char* ws = (char*)d_ws;
  float* temb        = (float*)ws;                              // 32 KB
  unsigned short* wb = (unsigned short*)(ws + 32768);           // 512 KB (q,k,v,p)
  unsigned short* xb = (unsigned short*)(ws + 557056);          // 16 MB
  unsigned short* qb = (unsigned short*)(ws + 17334272);        // 16 MB
  unsigned short* kb = (unsigned short*)(ws + 34111488);        // 16 MB
  unsigned short* vtb = (unsigned short*)(ws + 50888704);       // 16 MB [N, D, S]
  unsigned short* ob = (unsigned short*)(ws + 67665920);        // 16 MB
  unsigned short* projb = xb;                                   // reuse xb
  float* out = (float*)d_out;

  k_temb<<<32, 256, 0, stream>>>(t, Wt, bt, temb);
  k_wconv<<<1024, 256, 0, stream>>>(Wq, Wk, Wv, Wp, wb);
  k_addT<<<dim3(8, 32, 32), 256, 0, stream>>>(x, temb, xb);
  k_gemm<<<dim3(8, 2, 32), 256, 0, stream>>>(xb, wb,          qb,  0, SCALE);
  k_gemm<<<dim3(8, 2, 32), 256, 0, stream>>>(xb, wb + 65536,  kb,  0, 1.0f);
  k_gemm<<<dim3(8, 2, 32), 256, 0, stream>>>(xb, wb + 131072, vtb, 1, 1.0f);
  k_attn<<<256, 256, 0, stream>>>(qb, kb, vtb, ob);
  k_gemm<<<dim3(8, 2, 32), 256, 0, stream>>>(ob, wb + 196608, projb, 0, 1.0f);
  k_out<<<dim3(8, 32, 32), 256, 0, stream>>>(projb, x, bp, out);
}

// Round 5
// 144.256 us; speedup vs baseline: 2.4614x; 1.1858x over previous
//
#include <hip/hip_runtime.h>

#define NB 32
#define CD 256
#define SS 1024
#define DD 256
#define TT 512
#define SCALE 0.0625f

typedef __attribute__((ext_vector_type(8))) short s16x8;
typedef __attribute__((ext_vector_type(4))) short s16x4;
typedef __attribute__((ext_vector_type(4))) float f32x4;
typedef __attribute__((ext_vector_type(16))) float f32x16;

__device__ __forceinline__ unsigned short f2bf(float f) {
  unsigned u = __builtin_bit_cast(unsigned, f);
  u = (u + 0x7FFFu + ((u >> 16) & 1u)) >> 16;
  return (unsigned short)u;
}
__device__ __forceinline__ float bf2f(unsigned short h) {
  return __builtin_bit_cast(float, ((unsigned)h) << 16);
}

// ---- misc: blocks 0..1023 = weight fp32->bf16; 1024..1055 = temb ----
__global__ __launch_bounds__(256) void k_misc(const float* __restrict__ t,
    const float* __restrict__ Wt, const float* __restrict__ bt, float* __restrict__ temb,
    const float* __restrict__ wq, const float* __restrict__ wk,
    const float* __restrict__ wv, const float* __restrict__ wp,
    unsigned short* __restrict__ dst) {
  const int b = blockIdx.x;
  if (b < 1024) {
    const int i = b * 256 + threadIdx.x;
    const int which = i >> 16, off = i & 65535;
    const float* s = which == 0 ? wq : which == 1 ? wk : which == 2 ? wv : wp;
    dst[i] = f2bf(s[off]);
  } else {
    const int n = b - 1024, c = threadIdx.x;
    const float4* tv = (const float4*)(t + (size_t)n * TT);
    const float4* wvv = (const float4*)(Wt + (size_t)c * TT);
    float acc = 0.f;
#pragma unroll 8
    for (int i = 0; i < TT / 4; ++i) {
      float4 a = tv[i], bb = wvv[i];
      acc += a.x * bb.x + a.y * bb.y + a.z * bb.z + a.w * bb.w;
    }
    acc += bt[c];
    temb[n * CD + c] = fmaxf(acc, 0.f);
  }
}

// ---- xb[n, s, c] = bf16(x[n,c,s] + temb[n,c]) ; s = h*32+w (natural order) ----
__global__ __launch_bounds__(256) void k_addT(const float* __restrict__ x,
    const float* __restrict__ temb, unsigned short* __restrict__ xb) {
  __shared__ float tile[32][33];
  const int tx = threadIdx.x & 31, ty = threadIdx.x >> 5;
  const int n = blockIdx.z, s0 = blockIdx.y * 32, c0 = blockIdx.x * 32;
#pragma unroll
  for (int i = 0; i < 4; ++i) {
    const int cc = ty + i * 8;
    tile[cc][tx] = x[((size_t)n * CD + c0 + cc) * SS + s0 + tx] + temb[n * CD + c0 + cc];
  }
  __syncthreads();
  unsigned short* op = xb + ((size_t)n * SS + s0) * CD + c0;
#pragma unroll
  for (int i = 0; i < 4; ++i) {
    const int ss = ty + i * 8;
    op[(size_t)ss * CD + tx] = f2bf(tile[tx][ss]);
  }
}

// ---- QKV GEMM: z = which*32 + n. Out[n,s,d] = osc * sum_c xb[n,s,c] W[d,c];
//      which==2 writes V transposed: vtb[n,d,s]. ----
__global__ __launch_bounds__(256) void k_qkv(const unsigned short* __restrict__ A,
    const unsigned short* __restrict__ wb, unsigned short* __restrict__ qb,
    unsigned short* __restrict__ kb, unsigned short* __restrict__ vtb) {
  __shared__ __attribute__((aligned(16))) unsigned short As[128 * 32];
  __shared__ __attribute__((aligned(16))) unsigned short Bs[128 * 32];
  const int which = blockIdx.z >> 5, n = blockIdx.z & 31;
  const int s0 = blockIdx.x * 128;
  const int d0 = blockIdx.y * 128;
  const unsigned short* B = wb + which * 65536;
  const int tid = threadIdx.x;
  const int lane = tid & 63, wid = tid >> 6;
  const int lo = lane & 15, hi = lane >> 4;
  const int wr = wid >> 1, wc = wid & 1;
  const unsigned short* An = A + (size_t)n * SS * CD;
  f32x4 acc[4][4] = {};
  for (int k0 = 0; k0 < CD; k0 += 32) {
#pragma unroll
    for (int i = 0; i < 2; ++i) {
      const int seg = i * 256 + wid * 64 + lane;
      const int row = seg >> 2, c8 = seg & 3;
      const unsigned short* ga = An + (size_t)(s0 + row) * CD + k0 + c8 * 8;
      __builtin_amdgcn_global_load_lds(
          (const __attribute__((address_space(1))) unsigned int*)(const void*)ga,
          (__attribute__((address_space(3))) unsigned int*)(void*)(As + (size_t)(i * 256 + wid * 64) * 8),
          16, 0, 0);
      const unsigned short* gb = B + (size_t)(d0 + row) * CD + k0 + c8 * 8;
      __builtin_amdgcn_global_load_lds(
          (const __attribute__((address_space(1))) unsigned int*)(const void*)gb,
          (__attribute__((address_space(3))) unsigned int*)(void*)(Bs + (size_t)(i * 256 + wid * 64) * 8),
          16, 0, 0);
    }
    __syncthreads();
    s16x8 a[4], b[4];
#pragma unroll
    for (int mi = 0; mi < 4; ++mi)
      a[mi] = *(const s16x8*)&As[(wr * 64 + mi * 16 + lo) * 32 + hi * 8];
#pragma unroll
    for (int ni = 0; ni < 4; ++ni)
      b[ni] = *(const s16x8*)&Bs[(wc * 64 + ni * 16 + lo) * 32 + hi * 8];
#pragma unroll
    for (int mi = 0; mi < 4; ++mi)
#pragma unroll
      for (int ni = 0; ni < 4; ++ni)
        acc[mi][ni] = __builtin_amdgcn_mfma_f32_16x16x32_bf16(a[mi], b[ni], acc[mi][ni], 0, 0, 0);
    __syncthreads();
  }
  if (which < 2) {
    const float osc = which == 0 ? SCALE : 1.0f;
    unsigned short* On = (which == 0 ? qb : kb) + (size_t)n * SS * DD;
#pragma unroll
    for (int mi = 0; mi < 4; ++mi) {
      const int r0 = s0 + wr * 64 + mi * 16 + hi * 4;
#pragma unroll
      for (int ni = 0; ni < 4; ++ni) {
        const int col = d0 + wc * 64 + ni * 16 + lo;
#pragma unroll
        for (int r = 0; r < 4; ++r)
          On[(size_t)(r0 + r) * DD + col] = f2bf(acc[mi][ni][r] * osc);
      }
    }
  } else {
    unsigned short* On = vtb + (size_t)n * DD * SS;
#pragma unroll
    for (int mi = 0; mi < 4; ++mi) {
      const int r0 = s0 + wr * 64 + mi * 16 + hi * 4;
#pragma unroll
      for (int ni = 0; ni < 4; ++ni) {
        const int col = d0 + wc * 64 + ni * 16 + lo;
        s16x4 v;
#pragma unroll
        for (int r = 0; r < 4; ++r) v[r] = (short)f2bf(acc[mi][ni][r]);
        *(s16x4*)&On[(size_t)col * SS + r0] = v;
      }
    }
  }
}

// ---- flash attention, swapped-operand 32x32 MFMA, in-register softmax.
// grid 512: qt = bid&7, dh = (bid>>3)&1, n = bid>>4. 4 waves x 32 q-rows.
// Lane owns q = lane&31. K/V^T in LDS (KVBLK=32, dbuf, XOR-swizzled).
// P routed via per-wave LDS [32][40] (no permlane; crow-mapped stores). ----
__global__ __launch_bounds__(256, 2) void k_attn(const unsigned short* __restrict__ qb,
    const unsigned short* __restrict__ kb, const unsigned short* __restrict__ vtb,
    unsigned short* __restrict__ ob) {
  // ushort elems: Ks[2][8192] @0, Vs[2][4096] @16384, P[4][32*40] @24576
  __shared__ __attribute__((aligned(16))) unsigned short lds[29696];  // 58KB
  const int bid = blockIdx.x;
  const int qt = bid & 7, dh = (bid >> 3) & 1, n = bid >> 4;
  const int tid = threadIdx.x, lane = tid & 63, w = tid >> 6;
  const int l31 = lane & 31, h = lane >> 5;
  const int dblk = dh * 128;
  const unsigned short* Kn = kb + (size_t)n * SS * DD;
  const unsigned short* Vn = vtb + ((size_t)n * DD + dblk) * SS;
  unsigned short* Pw = lds + 24576 + w * 1280;  // [32][40]
  const int qrow = qt * 128 + w * 32 + l31;

  // Q fragments (B-operand): lane holds Q[q=qrow][k = ks*16 + h*8 + e]
  const unsigned short* Qp = qb + ((size_t)n * SS + qrow) * DD + h * 8;
  s16x8 qf[16];
#pragma unroll
  for (int ks = 0; ks < 16; ++ks) qf[ks] = *(const s16x8*)(Qp + ks * 16);

  f32x16 acc[4] = {};
  float mrun = -3.0e38f, lrun = 0.f;

  auto STAGE = [&](int buf, int jt) {
    const int j0 = jt * 32;
    unsigned short* KsB = lds + buf * 8192;
    unsigned short* VsB = lds + 16384 + buf * 4096;
#pragma unroll
    for (int i = 0; i < 4; ++i) {  // K: 32 rows x 256 cols
      const int idx = i * 256 + w * 64 + lane;
      const int row = idx >> 5, c8 = idx & 31;
      const unsigned short* g = Kn + (size_t)(j0 + row) * DD + ((c8 ^ (row & 7)) << 3);
      __builtin_amdgcn_global_load_lds(
          (const __attribute__((address_space(1))) unsigned int*)(const void*)g,
          (__attribute__((address_space(3))) unsigned int*)(void*)(KsB + (size_t)(i * 256 + w * 64) * 8),
          16, 0, 0);
    }
#pragma unroll
    for (int i = 0; i < 2; ++i) {  // V^T: 128 d-rows x 32 j-cols
      const int idx = i * 256 + w * 64 + lane;
      const int row = idx >> 2, c8 = idx & 3;
      const unsigned short* g = Vn + (size_t)row * SS + j0 + ((c8 ^ ((row >> 1) & 3)) << 3);
      __builtin_amdgcn_global_load_lds(
          (const __attribute__((address_space(1))) unsigned int*)(const void*)g,
          (__attribute__((address_space(3))) unsigned int*)(void*)(VsB + (size_t)(i * 256 + w * 64) * 8),
          16, 0, 0);
    }
  };

  STAGE(0, 0);
  __syncthreads();

  int cur = 0;
#pragma unroll 1
  for (int jt = 0; jt < 32; ++jt) {
    if (jt + 1 < 32) STAGE(cur ^ 1, jt + 1);
    const unsigned short* Ks = lds + cur * 8192;
    const unsigned short* Vs = lds + 16384 + cur * 4096;
    // ---- QK^T (swapped): lane holds S[j=crow(reg,h)][q=l31], crow=(r&3)+8*(r>>2)+4h
    f32x16 sc = {};
    __builtin_amdgcn_s_setprio(1);
#pragma unroll
    for (int ks = 0; ks < 16; ++ks) {
      const s16x8 kf = *(const s16x8*)&Ks[l31 * 256 + ((((ks * 2 + h)) ^ (l31 & 7)) << 3)];
      sc = __builtin_amdgcn_mfma_f32_32x32x16_bf16(kf, qf[ks], sc, 0, 0, 0);
    }
    __builtin_amdgcn_s_setprio(0);
    // ---- online softmax; row = pair {lane, lane^32}; one shfl per tile ----
    float pm = sc[0];
#pragma unroll
    for (int i = 1; i < 16; ++i) pm = fmaxf(pm, sc[i]);
    pm = fmaxf(pm, __shfl_xor(pm, 32, 64));
    if (__any(pm > mrun + 8.f)) {
      const float mn = fmaxf(mrun, pm);
      const float corr = __expf(mrun - mn);
      mrun = mn; lrun *= corr;
#pragma unroll
      for (int dc = 0; dc < 4; ++dc)
#pragma unroll
        for (int i = 0; i < 16; ++i) acc[dc][i] *= corr;
    }
#pragma unroll
    for (int i = 0; i < 16; ++i) sc[i] = __expf(sc[i] - mrun);
    lrun += (((sc[0] + sc[1]) + (sc[2] + sc[3])) + ((sc[4] + sc[5]) + (sc[6] + sc[7]))) +
            (((sc[8] + sc[9]) + (sc[10] + sc[11])) + ((sc[12] + sc[13]) + (sc[14] + sc[15])));
    // ---- P -> per-wave LDS at [q][crow]: store t covers cols 8t+4h..+3 ----
#pragma unroll
    for (int t = 0; t < 4; ++t) {
      s16x4 pv;
#pragma unroll
      for (int i = 0; i < 4; ++i) pv[i] = (short)f2bf(sc[t * 4 + i]);
      *(s16x4*)&Pw[l31 * 40 + t * 8 + h * 4] = pv;
    }
    // read A-fragments: pa0 = P[q][h*8 + e], pa1 = P[q][16 + h*8 + e]
    const s16x8 pa0 = *(const s16x8*)&Pw[l31 * 40 + h * 8];
    const s16x8 pa1 = *(const s16x8*)&Pw[l31 * 40 + 16 + h * 8];
    // ---- PV: acc[dc] += V^T-frag x P-frag  (O lane-owns q = l31) ----
    __builtin_amdgcn_s_setprio(1);
#pragma unroll
    for (int dc = 0; dc < 4; ++dc) {
      const s16x8 vf0 = *(const s16x8*)&Vs[(dc * 32 + l31) * 32 + ((h ^ ((l31 >> 1) & 3)) << 3)];
      acc[dc] = __builtin_amdgcn_mfma_f32_32x32x16_bf16(vf0, pa0, acc[dc], 0, 0, 0);
    }
#pragma unroll
    for (int dc = 0; dc < 4; ++dc) {
      const s16x8 vf1 = *(const s16x8*)&Vs[(dc * 32 + l31) * 32 + (((2 + h) ^ ((l31 >> 1) & 3)) << 3)];
      acc[dc] = __builtin_amdgcn_mfma_f32_32x32x16_bf16(vf1, pa1, acc[dc], 0, 0, 0);
    }
    __builtin_amdgcn_s_setprio(0);
    __syncthreads();
    cur ^= 1;
  }
  lrun += __shfl_xor(lrun, 32, 64);
  const float inv = 1.0f / lrun;
  unsigned short* Op = ob + ((size_t)n * SS + qrow) * DD + dblk;
#pragma unroll
  for (int dc = 0; dc < 4; ++dc)
#pragma unroll
    for (int rg = 0; rg < 4; ++rg) {
      s16x4 v;
#pragma unroll
      for (int i = 0; i < 4; ++i) v[i] = (short)f2bf(acc[dc][rg * 4 + i] * inv);
      *(s16x4*)(Op + dc * 32 + rg * 8 + h * 4) = v;
    }
}

// ---- fused proj + bias + residual: out[n,c,s] = sum_d ob[n,s,d] Wp[c,d] + bp[c] + x[n,c,s]
__global__ __launch_bounds__(256) void k_proj(const unsigned short* __restrict__ ob,
    const unsigned short* __restrict__ wpb, const float* __restrict__ bp,
    const float* __restrict__ x, float* __restrict__ out) {
  __shared__ __attribute__((aligned(16))) unsigned short As[128 * 32];
  __shared__ __attribute__((aligned(16))) unsigned short Bs[128 * 32];
  const int n = blockIdx.z;
  const int s0 = blockIdx.x * 128;
  const int c0 = blockIdx.y * 128;
  const int tid = threadIdx.x;
  const int lane = tid & 63, wid = tid >> 6;
  const int lo = lane & 15, hi = lane >> 4;
  const int wr = wid >> 1, wc = wid & 1;
  const unsigned short* On = ob + (size_t)n * SS * DD;
  f32x4 acc[4][4] = {};
  for (int k0 = 0; k0 < DD; k0 += 32) {
#pragma unroll
    for (int i = 0; i < 2; ++i) {
      const int seg = i * 256 + wid * 64 + lane;
      const int row = seg >> 2, c8 = seg & 3;
      const unsigned short* ga = wpb + (size_t)(c0 + row) * DD + k0 + c8 * 8;
      __builtin_amdgcn_global_load_lds(
          (const __attribute__((address_space(1))) unsigned int*)(const void*)ga,
          (__attribute__((address_space(3))) unsigned int*)(void*)(As + (size_t)(i * 256 + wid * 64) * 8),
          16, 0, 0);
      const unsigned short* gb = On + (size_t)(s0 + row) * DD + k0 + c8 * 8;
      __builtin_amdgcn_global_load_lds(
          (const __attribute__((address_space(1))) unsigned int*)(const void*)gb,
          (__attribute__((address_space(3))) unsigned int*)(void*)(Bs + (size_t)(i * 256 + wid * 64) * 8),
          16, 0, 0);
    }
    __syncthreads();
    s16x8 a[4], b[4];
#pragma unroll
    for (int mi = 0; mi < 4; ++mi)
      a[mi] = *(const s16x8*)&As[(wr * 64 + mi * 16 + lo) * 32 + hi * 8];
#pragma unroll
    for (int ni = 0; ni < 4; ++ni)
      b[ni] = *(const s16x8*)&Bs[(wc * 64 + ni * 16 + lo) * 32 + hi * 8];
#pragma unroll
    for (int mi = 0; mi < 4; ++mi)
#pragma unroll
      for (int ni = 0; ni < 4; ++ni)
        acc[mi][ni] = __builtin_amdgcn_mfma_f32_16x16x32_bf16(a[mi], b[ni], acc[mi][ni], 0, 0, 0);
    __syncthreads();
  }
  // acc[mi][ni][r] = OutT[c][s], c = c0+wr*64+mi*16+hi*4+r, s = s0+wc*64+ni*16+lo
#pragma unroll
  for (int mi = 0; mi < 4; ++mi) {
#pragma unroll
    for (int r = 0; r < 4; ++r) {
      const int c = c0 + wr * 64 + mi * 16 + hi * 4 + r;
      const float bpc = bp[c];
      const size_t base = ((size_t)n * CD + c) * SS;
#pragma unroll
      for (int ni = 0; ni < 4; ++ni) {
        const int s = s0 + wc * 64 + ni * 16 + lo;
        out[base + s] = acc[mi][ni][r] + bpc + x[base + s];
      }
    }
  }
}

extern "C" void kernel_launch(void* const* d_in, const int* in_sizes, int n_in,
                              void* d_out, int out_size, void* d_ws, size_t ws_size,
                              hipStream_t stream) {
  const float* x  = (const float*)d_in[0];
  const float* t  = (const float*)d_in[1];
  const float* Wt = (const float*)d_in[2];
  const float* bt = (const float*)d_in[3];
  const float* Wq = (const float*)d_in[4];
  const float* Wk = (const float*)d_in[5];
  const float* Wv = (const float*)d_in[6];
  const float* Wp = (const float*)d_in[7];
  const float* bp = (const float*)d_in[8];
  char* ws = (char*)d_ws;
  float* temb        = (float*)ws;                              // 32 KB
  unsigned short* wb = (unsigned short*)(ws + 32768);           // 512 KB (q,k,v,p)
  unsigned short* xb = (unsigned short*)(ws + 557056);          // 16 MB [n,s,c]
  unsigned short* qb = (unsigned short*)(ws + 17334272);        // 16 MB [n,s,d]
  unsigned short* kb = (unsigned short*)(ws + 34111488);        // 16 MB [n,s,d]
  unsigned short* vtb = (unsigned short*)(ws + 50888704);       // 16 MB [n,d,s]
  unsigned short* ob = (unsigned short*)(ws + 67665920);        // 16 MB [n,s,d]
  float* out = (float*)d_out;

  k_misc<<<1056, 256, 0, stream>>>(t, Wt, bt, temb, Wq, Wk, Wv, Wp, wb);
  k_addT<<<dim3(8, 32, 32), 256, 0, stream>>>(x, temb, xb);
  k_qkv<<<dim3(8, 2, 96), 256, 0, stream>>>(xb, wb, qb, kb, vtb);
  k_attn<<<512, 256, 0, stream>>>(qb, kb, vtb, ob);
  k_proj<<<dim3(8, 2, 32), 256, 0, stream>>>(ob, wb + 196608, bp, x, out);
}